// Round 6
// baseline (196.593 us; speedup 1.0000x reference)
//
#include <hip/hip_runtime.h>

#define Bb 64
#define Nn 1152
#define Oo 32
#define DOv 16
#define DIv 8
#define BPB 16   // b's per block: 8 half-waves x 2 b's

// async global->LDS, 16B per lane
__device__ __forceinline__ void gload_lds16(const void* g, void* l) {
    __builtin_amdgcn_global_load_lds(
        (const __attribute__((address_space(1))) unsigned*)g,
        (__attribute__((address_space(3))) unsigned*)l, 16, 0, 0);
}

// One routing iteration, NC n's per block, triple-buffered W staging with
// counted vmcnt (8 loads in flight across raw s_barriers; never drained to 0
// mid-loop). Lane layout: o = t&31, bl = t>>5 (0..7); thread covers b0+bl and
// b0+8+bl. vcum == nullptr -> uniform c = 1/32 (iteration 1).
template<int NC>
__global__ __launch_bounds__(256, 2) void caps_route(
    const float* __restrict__ x,     // [B, N, DI]
    const float* __restrict__ w,     // [N, O, DO, DI]
    const float* __restrict__ vcum,  // [B, O, DO] or nullptr
    float* __restrict__ spart)       // [nch, B, O, DO]
{
    const int t  = threadIdx.x;
    const int o  = t & 31;
    const int bl = t >> 5;            // 0..7
    const int n0 = blockIdx.x * NC;
    const int b0 = blockIdx.y * BPB;

    // wbuf phys float4 slot o*32 + (i2^o) holds logical w[n][o][i2] (XOR bank
    // swizzle). LDS dest of global_load_lds stays lane-linear; the GLOBAL index
    // is pre-swizzled (gq). Triple-buffered: stage(nn+2) after barrier nn.
    __shared__ float4 wbuf[3][1024];      // 48 KB
    __shared__ float4 xbuf[NC][BPB][2];   // 4 KB for NC=8

    int gq[4];
#pragma unroll
    for (int k = 0; k < 4; ++k) {
        int p = k * 256 + t;
        gq[k] = (p & ~31) | ((p ^ (p >> 5)) & 31);
    }
    auto stageW = [&](int n, int c) {
        const float4* wg = (const float4*)(w + (size_t)n * (Oo * DOv * DIv));
#pragma unroll
        for (int k = 0; k < 4; ++k)
            gload_lds16(&wg[gq[k]], &wbuf[c][k * 256 + t]);
    };

    // stage all NC x-tiles once (NC*BPB*2 = 256 float4 for NC=8: one per thread)
    for (int q = t; q < NC * BPB * 2; q += 256) {
        int nn = q >> 5, bb = (q >> 1) & 15, h = q & 1;
        xbuf[nn][bb][h] = ((const float4*)(
            x + ((size_t)(b0 + bb) * Nn + (size_t)(n0 + nn)) * DIv))[h];
    }

    const bool have_v = (vcum != nullptr);
    float vc0[DOv], vc1[DOv];
    if (have_v) {
#pragma unroll
        for (int i = 0; i < DOv; ++i) vc0[i] = vcum[((size_t)(b0 + bl) * Oo + o) * DOv + i];
#pragma unroll
        for (int i = 0; i < DOv; ++i) vc1[i] = vcum[((size_t)(b0 + 8 + bl) * Oo + o) * DOv + i];
    }

    float sacc0[DOv], sacc1[DOv];
#pragma unroll
    for (int i = 0; i < DOv; ++i) { sacc0[i] = 0.f; sacc1[i] = 0.f; }

    __syncthreads();                 // xbuf visible to all waves
    stageW(n0 + 0, 0);               // 4 loads
    stageW(n0 + 1, 1);               // 8 loads in flight

#pragma unroll
    for (int nn = 0; nn < NC; ++nn) {
        // steady state: outstanding = stage(nn) + stage(nn+1) = 8 loads.
        // vmcnt(4) completes stage(nn), leaves stage(nn+1) flying.
        if (nn < NC - 1) asm volatile("s_waitcnt vmcnt(4)" ::: "memory");
        else             asm volatile("s_waitcnt vmcnt(0)" ::: "memory");
        __builtin_amdgcn_s_barrier();      // wbuf[nn%3] ready on every wave
        // buffer (nn+2)%3 == (nn-1)%3 was last read at iter nn-1: freed by the
        // barrier above -> safe to restage now (no wave can still be reading it).
        if (nn + 2 < NC) stageW(n0 + nn + 2, (nn + 2) % 3);

        const float* xs = (const float*)xbuf[nn];
        float xa[DIv], xb[DIv];
#pragma unroll
        for (int j = 0; j < DIv; ++j) { xa[j] = xs[bl * DIv + j]; xb[j] = xs[(8 + bl) * DIv + j]; }

        float xh0[DOv], xh1[DOv];
#pragma unroll
        for (int i = 0; i < DOv; ++i) { xh0[i] = 0.f; xh1[i] = 0.f; }
#pragma unroll
        for (int i2 = 0; i2 < 32; ++i2) {
            float4 wv = wbuf[nn % 3][o * 32 + (i2 ^ o)];   // = w[n][o][i2*4 .. +3]
            const int i = i2 >> 1, jb = (i2 & 1) * 4;
            xh0[i] = fmaf(wv.x, xa[jb + 0], xh0[i]);
            xh0[i] = fmaf(wv.y, xa[jb + 1], xh0[i]);
            xh0[i] = fmaf(wv.z, xa[jb + 2], xh0[i]);
            xh0[i] = fmaf(wv.w, xa[jb + 3], xh0[i]);
            xh1[i] = fmaf(wv.x, xb[jb + 0], xh1[i]);
            xh1[i] = fmaf(wv.y, xb[jb + 1], xh1[i]);
            xh1[i] = fmaf(wv.z, xb[jb + 2], xh1[i]);
            xh1[i] = fmaf(wv.w, xb[jb + 3], xh1[i]);
        }

        float c0, c1;
        if (have_v) {
            float l0 = 0.f, l1 = 0.f;
#pragma unroll
            for (int i = 0; i < DOv; ++i) { l0 += xh0[i] * vc0[i]; l1 += xh1[i] * vc1[i]; }
            float e0 = __expf(l0), e1 = __expf(l1);   // |l| < 1: no max-sub needed
            float s0 = e0, s1 = e1;
#pragma unroll
            for (int d = 16; d >= 1; d >>= 1) {
                s0 += __shfl_xor(s0, d);
                s1 += __shfl_xor(s1, d);
            }
            c0 = e0 / s0; c1 = e1 / s1;
        } else {
            c0 = 1.0f / 32.0f; c1 = 1.0f / 32.0f;
        }

#pragma unroll
        for (int i = 0; i < DOv; ++i) { sacc0[i] += c0 * xh0[i]; sacc1[i] += c1 * xh1[i]; }
    }

    // plain float4 stores of this chunk's partial (no atomics)
    float* p  = spart + (size_t)blockIdx.x * (Bb * Oo * DOv);
    float* p0 = p + ((size_t)(b0 + bl) * Oo + o) * DOv;
    float* p1 = p + ((size_t)(b0 + 8 + bl) * Oo + o) * DOv;
#pragma unroll
    for (int q = 0; q < 4; ++q)
        ((float4*)p0)[q] = make_float4(sacc0[4*q], sacc0[4*q+1], sacc0[4*q+2], sacc0[4*q+3]);
#pragma unroll
    for (int q = 0; q < 4; ++q)
        ((float4*)p1)[q] = make_float4(sacc1[4*q], sacc1[4*q+1], sacc1[4*q+2], sacc1[4*q+3]);
}

// Reduce nch partials + squash. One wave per (b, o); float4 lanes: q = t&3, pg = t>>2.
__global__ __launch_bounds__(64) void caps_squash(
    const float* __restrict__ spart, int nch,
    const float* __restrict__ vin,   // may be nullptr (treated as 0)
    float* __restrict__ vout,        // may be nullptr
    float* __restrict__ out)         // may be nullptr
{
    const int b = blockIdx.x, oo = blockIdx.y;
    const int t = threadIdx.x;
    const int q = t & 3, pg = t >> 2;          // 16 p-groups
    const size_t base4 = ((size_t)b * Oo + oo) * (DOv / 4) + q;
    const float4* sp4 = (const float4*)spart;
    const size_t chunk4 = (size_t)Bb * Oo * DOv / 4;

    float4 s = make_float4(0.f, 0.f, 0.f, 0.f);
    for (int p = pg; p < nch; p += 16) {
        float4 v = sp4[(size_t)p * chunk4 + base4];
        s.x += v.x; s.y += v.y; s.z += v.z; s.w += v.w;
    }
#pragma unroll
    for (int d = 4; d <= 32; d <<= 1) {
        s.x += __shfl_xor(s.x, d); s.y += __shfl_xor(s.y, d);
        s.z += __shfl_xor(s.z, d); s.w += __shfl_xor(s.w, d);
    }
    float n2 = s.x * s.x + s.y * s.y + s.z * s.z + s.w * s.w;
    n2 += __shfl_xor(n2, 1);
    n2 += __shfl_xor(n2, 2);
    float sc = n2 / ((1.f + n2) * sqrtf(n2 + 1e-7f));
    if (t < 4) {
        float4 vj = make_float4(s.x * sc, s.y * sc, s.z * sc, s.w * sc);
        size_t i4 = base4;
        if (vout) {
            float4 vi = vin ? ((const float4*)vin)[i4] : make_float4(0.f, 0.f, 0.f, 0.f);
            ((float4*)vout)[i4] = make_float4(vi.x + vj.x, vi.y + vj.y, vi.z + vj.z, vi.w + vj.w);
        }
        if (out) ((float4*)out)[i4] = vj;
    }
}

extern "C" void kernel_launch(void* const* d_in, const int* in_sizes, int n_in,
                              void* d_out, int out_size, void* d_ws, size_t ws_size,
                              hipStream_t stream)
{
    const float* x = (const float*)d_in[0];
    const float* w = (const float*)d_in[1];
    float* out = (float*)d_out;

    // primary: nch=144, NC=8 -> grid (144,4) = 576 blocks (2.25/CU), spart 18.9 MB.
    // 144 % 8 == 0: blocks sharing a W chunk land on the same XCD.
    int nch = 144;
    size_t need = ((size_t)nch * Bb * Oo * DOv + (size_t)Bb * Oo * DOv) * sizeof(float);
    if (need > ws_size) {  // fallback: tiny ws -> fewer chunks (NC=72)
        nch = 16;
    }

    float* spart = (float*)d_ws;
    float* vcum  = spart + (size_t)nch * Bb * Oo * DOv;

    dim3 blk(256);
    dim3 sgrid(Bb, Oo), sblk(64);

    if (nch == 144) {
        dim3 grid(144, Bb / BPB);
        caps_route<8><<<grid, blk, 0, stream>>>(x, w, nullptr, spart);
        caps_squash<<<sgrid, sblk, 0, stream>>>(spart, nch, nullptr, vcum, nullptr);
        caps_route<8><<<grid, blk, 0, stream>>>(x, w, vcum, spart);
        caps_squash<<<sgrid, sblk, 0, stream>>>(spart, nch, vcum, vcum, nullptr);
        caps_route<8><<<grid, blk, 0, stream>>>(x, w, vcum, spart);
        caps_squash<<<sgrid, sblk, 0, stream>>>(spart, nch, nullptr, nullptr, out);
    } else {
        dim3 grid(16, Bb / BPB);
        caps_route<72><<<grid, blk, 0, stream>>>(x, w, nullptr, spart);
        caps_squash<<<sgrid, sblk, 0, stream>>>(spart, nch, nullptr, vcum, nullptr);
        caps_route<72><<<grid, blk, 0, stream>>>(x, w, vcum, spart);
        caps_squash<<<sgrid, sblk, 0, stream>>>(spart, nch, vcum, vcum, nullptr);
        caps_route<72><<<grid, blk, 0, stream>>>(x, w, vcum, spart);
        caps_squash<<<sgrid, sblk, 0, stream>>>(spart, nch, nullptr, nullptr, out);
    }
}

// Round 7
// 123.933 us; speedup vs baseline: 1.5863x; 1.5863x over previous
//
#include <hip/hip_runtime.h>

#define Bb 64
#define Nn 1152
#define Oo 32
#define DOv 16
#define DIv 8
#define BPB 16   // b's per block: 8 half-waves x 2 b's

// async global->LDS, 16B per lane
__device__ __forceinline__ void gload_lds16(const void* g, void* l) {
    __builtin_amdgcn_global_load_lds(
        (const __attribute__((address_space(1))) unsigned*)g,
        (__attribute__((address_space(3))) unsigned*)l, 16, 0, 0);
}

// One routing iteration, NC n's per block. Round-3-proven structure:
// double-buffered W staging via global_load_lds, plain __syncthreads per n
// (stage-after-barrier is race-free: all LDS reads of the target buffer
// drained by the barrier; the next barrier's vmcnt(0) drains the stage).
// Lane layout: o = t&31, bl = t>>5; thread covers b0+bl and b0+8+bl.
// vcum == nullptr -> uniform c = 1/32 (iteration 1).
template<int NC>
__global__ __launch_bounds__(256) void caps_route(
    const float* __restrict__ x,     // [B, N, DI]
    const float* __restrict__ w,     // [N, O, DO, DI]
    const float* __restrict__ vcum,  // [B, O, DO] or nullptr
    float* __restrict__ spart)       // [nch, B, O, DO]
{
    const int t  = threadIdx.x;
    const int o  = t & 31;
    const int bl = t >> 5;            // 0..7
    const int n0 = blockIdx.x * NC;
    const int b0 = blockIdx.y * BPB;

    // wbuf phys float4 slot o*32 + (i2^o) holds logical w[n][o][i2] (XOR bank
    // swizzle -> conflict-free b128 reads). LDS dest of global_load_lds stays
    // lane-linear; the GLOBAL index is pre-swizzled (gq).
    __shared__ float4 wbuf[2][1024];      // 32 KB, double-buffered
    __shared__ float4 xbuf[NC][BPB][2];   // 2 KB for NC=4

    int gq[4];
#pragma unroll
    for (int k = 0; k < 4; ++k) {
        int p = k * 256 + t;
        gq[k] = (p & ~31) | ((p ^ (p >> 5)) & 31);
    }
    auto stageW = [&](int n, int c) {
        const float4* wg = (const float4*)(w + (size_t)n * (Oo * DOv * DIv));
#pragma unroll
        for (int k = 0; k < 4; ++k)
            gload_lds16(&wg[gq[k]], &wbuf[c][k * 256 + t]);
    };

    // stage all NC x-tiles once (NC*BPB*2 = 128 float4 for NC=4)
    for (int q = t; q < NC * BPB * 2; q += 256) {
        int nn = q >> 5, bb = (q >> 1) & 15, h = q & 1;
        xbuf[nn][bb][h] = ((const float4*)(
            x + ((size_t)(b0 + bb) * Nn + (size_t)(n0 + nn)) * DIv))[h];
    }

    const bool have_v = (vcum != nullptr);
    float vc0[DOv], vc1[DOv];
    if (have_v) {
#pragma unroll
        for (int i = 0; i < DOv; ++i) vc0[i] = vcum[((size_t)(b0 + bl) * Oo + o) * DOv + i];
#pragma unroll
        for (int i = 0; i < DOv; ++i) vc1[i] = vcum[((size_t)(b0 + 8 + bl) * Oo + o) * DOv + i];
    }

    float sacc0[DOv], sacc1[DOv];
#pragma unroll
    for (int i = 0; i < DOv; ++i) { sacc0[i] = 0.f; sacc1[i] = 0.f; }

    stageW(n0, 0);
    int cur = 0;

#pragma unroll
    for (int nn = 0; nn < NC; ++nn) {
        __syncthreads();                     // wbuf[cur] ready (vmcnt drained); xbuf visible
        if (nn + 1 < NC) stageW(n0 + nn + 1, cur ^ 1);  // fly under compute

        const float* xs = (const float*)xbuf[nn];
        float xa[DIv], xb[DIv];
#pragma unroll
        for (int j = 0; j < DIv; ++j) { xa[j] = xs[bl * DIv + j]; xb[j] = xs[(8 + bl) * DIv + j]; }

        float xh0[DOv], xh1[DOv];
#pragma unroll
        for (int i = 0; i < DOv; ++i) { xh0[i] = 0.f; xh1[i] = 0.f; }
#pragma unroll
        for (int i2 = 0; i2 < 32; ++i2) {
            float4 wv = wbuf[cur][o * 32 + (i2 ^ o)];   // = w[n][o][i2*4 .. +3]
            const int i = i2 >> 1, jb = (i2 & 1) * 4;
            xh0[i] = fmaf(wv.x, xa[jb + 0], xh0[i]);
            xh0[i] = fmaf(wv.y, xa[jb + 1], xh0[i]);
            xh0[i] = fmaf(wv.z, xa[jb + 2], xh0[i]);
            xh0[i] = fmaf(wv.w, xa[jb + 3], xh0[i]);
            xh1[i] = fmaf(wv.x, xb[jb + 0], xh1[i]);
            xh1[i] = fmaf(wv.y, xb[jb + 1], xh1[i]);
            xh1[i] = fmaf(wv.z, xb[jb + 2], xh1[i]);
            xh1[i] = fmaf(wv.w, xb[jb + 3], xh1[i]);
        }

        float c0, c1;
        if (have_v) {
            float l0 = 0.f, l1 = 0.f;
#pragma unroll
            for (int i = 0; i < DOv; ++i) { l0 += xh0[i] * vc0[i]; l1 += xh1[i] * vc1[i]; }
            float e0 = __expf(l0), e1 = __expf(l1);   // |l| < 1: no max-sub needed
            float s0 = e0, s1 = e1;
#pragma unroll
            for (int d = 16; d >= 1; d >>= 1) {
                s0 += __shfl_xor(s0, d);
                s1 += __shfl_xor(s1, d);
            }
            c0 = e0 / s0; c1 = e1 / s1;
        } else {
            c0 = 1.0f / 32.0f; c1 = 1.0f / 32.0f;
        }

#pragma unroll
        for (int i = 0; i < DOv; ++i) { sacc0[i] += c0 * xh0[i]; sacc1[i] += c1 * xh1[i]; }
        cur ^= 1;
    }

    // plain float4 stores of this chunk's partial (no atomics)
    float* p  = spart + (size_t)blockIdx.x * (Bb * Oo * DOv);
    float* p0 = p + ((size_t)(b0 + bl) * Oo + o) * DOv;
    float* p1 = p + ((size_t)(b0 + 8 + bl) * Oo + o) * DOv;
#pragma unroll
    for (int q = 0; q < 4; ++q)
        ((float4*)p0)[q] = make_float4(sacc0[4*q], sacc0[4*q+1], sacc0[4*q+2], sacc0[4*q+3]);
#pragma unroll
    for (int q = 0; q < 4; ++q)
        ((float4*)p1)[q] = make_float4(sacc1[4*q], sacc1[4*q+1], sacc1[4*q+2], sacc1[4*q+3]);
}

// Reduce nch partials + squash. One wave per (b, o); float4 lanes: q = t&3, pg = t>>2.
__global__ __launch_bounds__(64) void caps_squash(
    const float* __restrict__ spart, int nch,
    const float* __restrict__ vin,   // may be nullptr (treated as 0)
    float* __restrict__ vout,        // may be nullptr
    float* __restrict__ out)         // may be nullptr
{
    const int b = blockIdx.x, oo = blockIdx.y;
    const int t = threadIdx.x;
    const int q = t & 3, pg = t >> 2;          // 16 p-groups
    const size_t base4 = ((size_t)b * Oo + oo) * (DOv / 4) + q;
    const float4* sp4 = (const float4*)spart;
    const size_t chunk4 = (size_t)Bb * Oo * DOv / 4;

    float4 s = make_float4(0.f, 0.f, 0.f, 0.f);
    for (int p = pg; p < nch; p += 16) {
        float4 v = sp4[(size_t)p * chunk4 + base4];
        s.x += v.x; s.y += v.y; s.z += v.z; s.w += v.w;
    }
#pragma unroll
    for (int d = 4; d <= 32; d <<= 1) {
        s.x += __shfl_xor(s.x, d); s.y += __shfl_xor(s.y, d);
        s.z += __shfl_xor(s.z, d); s.w += __shfl_xor(s.w, d);
    }
    float n2 = s.x * s.x + s.y * s.y + s.z * s.z + s.w * s.w;
    n2 += __shfl_xor(n2, 1);
    n2 += __shfl_xor(n2, 2);
    float sc = n2 / ((1.f + n2) * sqrtf(n2 + 1e-7f));
    if (t < 4) {
        float4 vj = make_float4(s.x * sc, s.y * sc, s.z * sc, s.w * sc);
        size_t i4 = base4;
        if (vout) {
            float4 vi = vin ? ((const float4*)vin)[i4] : make_float4(0.f, 0.f, 0.f, 0.f);
            ((float4*)vout)[i4] = make_float4(vi.x + vj.x, vi.y + vj.y, vi.z + vj.z, vi.w + vj.w);
        }
        if (out) ((float4*)out)[i4] = vj;
    }
}

extern "C" void kernel_launch(void* const* d_in, const int* in_sizes, int n_in,
                              void* d_out, int out_size, void* d_ws, size_t ws_size,
                              hipStream_t stream)
{
    const float* x = (const float*)d_in[0];
    const float* w = (const float*)d_in[1];
    float* out = (float*)d_out;

    // primary: nch=288, NC=4 -> grid (288,4) = 1152 blocks (~4.5/CU, 16 waves/CU
    // with 34 KB LDS + ~110 VGPR). spart = 37.7 MB. 288 % 8 == 0: W-sharing
    // y-blocks co-land per XCD.
    int nch = 288;
    size_t need = ((size_t)nch * Bb * Oo * DOv + (size_t)Bb * Oo * DOv) * sizeof(float);
    if (need > ws_size) nch = 144;       // fallback for small ws
    size_t need2 = ((size_t)nch * Bb * Oo * DOv + (size_t)Bb * Oo * DOv) * sizeof(float);
    if (need2 > ws_size) nch = 16;       // last resort

    float* spart = (float*)d_ws;
    float* vcum  = spart + (size_t)nch * Bb * Oo * DOv;

    dim3 blk(256);
    dim3 sgrid(Bb, Oo), sblk(64);
    dim3 grid(nch, Bb / BPB);

    if (nch == 288) {
        caps_route<4><<<grid, blk, 0, stream>>>(x, w, nullptr, spart);
        caps_squash<<<sgrid, sblk, 0, stream>>>(spart, nch, nullptr, vcum, nullptr);
        caps_route<4><<<grid, blk, 0, stream>>>(x, w, vcum, spart);
        caps_squash<<<sgrid, sblk, 0, stream>>>(spart, nch, vcum, vcum, nullptr);
        caps_route<4><<<grid, blk, 0, stream>>>(x, w, vcum, spart);
        caps_squash<<<sgrid, sblk, 0, stream>>>(spart, nch, nullptr, nullptr, out);
    } else if (nch == 144) {
        caps_route<8><<<grid, blk, 0, stream>>>(x, w, nullptr, spart);
        caps_squash<<<sgrid, sblk, 0, stream>>>(spart, nch, nullptr, vcum, nullptr);
        caps_route<8><<<grid, blk, 0, stream>>>(x, w, vcum, spart);
        caps_squash<<<sgrid, sblk, 0, stream>>>(spart, nch, vcum, vcum, nullptr);
        caps_route<8><<<grid, blk, 0, stream>>>(x, w, vcum, spart);
        caps_squash<<<sgrid, sblk, 0, stream>>>(spart, nch, nullptr, nullptr, out);
    } else {
        caps_route<72><<<grid, blk, 0, stream>>>(x, w, nullptr, spart);
        caps_squash<<<sgrid, sblk, 0, stream>>>(spart, nch, nullptr, vcum, nullptr);
        caps_route<72><<<grid, blk, 0, stream>>>(x, w, vcum, spart);
        caps_squash<<<sgrid, sblk, 0, stream>>>(spart, nch, vcum, vcum, nullptr);
        caps_route<72><<<grid, blk, 0, stream>>>(x, w, vcum, spart);
        caps_squash<<<sgrid, sblk, 0, stream>>>(spart, nch, nullptr, nullptr, out);
    }
}